// Round 1
// 1468.346 us; speedup vs baseline: 1.1337x; 1.1337x over previous
//
#include <hip/hip_runtime.h>
#include <stdint.h>

// ---- types ----
typedef __bf16  bf16x8 __attribute__((ext_vector_type(8)));
typedef unsigned short u16x8 __attribute__((ext_vector_type(8)));
typedef float   f32x4  __attribute__((ext_vector_type(4)));

__device__ __forceinline__ unsigned short f2b(float f) {
  union { float f; uint32_t u; } v; v.f = f;
  uint32_t r = v.u + 0x7fffu + ((v.u >> 16) & 1u);   // RNE
  return (unsigned short)(r >> 16);
}
__device__ __forceinline__ float b2f(unsigned short u) {
  union { uint32_t u; float f; } v; v.u = ((uint32_t)u) << 16;
  return v.f;
}

// async global->LDS, 16B per lane, wave-uniform LDS base (lane i lands at base+i*16)
#define GLDS16(gp, lp) __builtin_amdgcn_global_load_lds( \
    (const __attribute__((address_space(1))) void*)(gp), \
    (__attribute__((address_space(3))) void*)(lp), 16, 0, 0)

// =====================================================================
// 256x256-tile, BK=64, 8-wave (2x4), 8-phase deep-pipelined bf16 GEMM.
//   C = A[M,K] @ Bt[N,K]^T, K % 64 == 0, K >= 128.
// LDS (static 128KB): 2 K-tile dbuf x {A,B} x 2 k-halves of [256 r][32 k].
//   Region element layout: r*32 + slot*8, slot = c ^ ((r>>1)&3)  (c = k/8).
//   -> ds_read_b128 frag reads: per 16-lane group all 8 bank-quads hit 2x
//      (2-way = free). Staging stays DMA-linear; the swizzle is applied to
//      the per-lane GLOBAL source address (both-sides-or-neither rule).
// Phase p of K-tile t: {ds_read subtile; stage ONE 16KB granule; barrier;
//   lgkmcnt(0); setprio(1); 16 MFMA; setprio(0); barrier}.
// Stage schedule (each granule issued >=6 phases before first use, and only
// into a region whose last reader finished at the previous phase barrier):
//   ph1 -> (t+1).B.k1   ph2 -> (t+2).A.k0   ph3 -> (t+2).B.k0   ph4 -> (t+2).A.k1
// vmcnt(6) once per K-tile (phase 4) == 3 granules in flight; guarantees all
// of tile t+1 landed. Drain vmcnt(0) only at t == NT-2.
// =====================================================================
template <class Epi>
__device__ __forceinline__ void gemm256(
    unsigned short* lds,
    const unsigned short* __restrict__ A, int lda,
    const unsigned short* __restrict__ Bt, int ldb,
    int K, int r0, int c0, Epi epi)
{
  const int tid  = threadIdx.x;
  const int lane = tid & 63;
  const int wave = tid >> 6;
  const int wm   = wave >> 2;          // 0..1   (output rows wm*128 ..)
  const int wn   = wave & 3;           // 0..3   (output cols wn*64 ..)
  const int quad = lane >> 4;
  const int lm   = lane & 15;
  const int sw   = (quad ^ ((lm >> 1) & 3)) * 8;  // swizzled chunk offset (elems)
  const int NT   = K >> 6;

  // staging geometry: per 16KB granule each thread DMAs 2 chunks of 16B.
  // linear LDS chunk ci -> row r = ci>>2, slot = ci&3 holds global chunk
  // c = slot ^ ((r>>1)&3).
  size_t gA[2], gB[2];
  int ldso[2];
#pragma unroll
  for (int s = 0; s < 2; s++) {
    int ci = wave * 128 + s * 64 + lane;
    int r  = ci >> 2;
    int c  = (ci & 3) ^ ((r >> 1) & 3);
    gA[s]   = (size_t)(r0 + r) * lda + c * 8;
    gB[s]   = (size_t)(c0 + r) * ldb + c * 8;
    ldso[s] = (wave * 2 + s) * 512;
  }

#define STG_A(t, kh) do { if ((t) < NT) {                         \
    int _b = ((t) & 1) * 32768 + (kh) * 8192;                     \
    size_t _ko = (size_t)(t) * 64 + (kh) * 32;                    \
    GLDS16(A + gA[0] + _ko, lds + _b + ldso[0]);                  \
    GLDS16(A + gA[1] + _ko, lds + _b + ldso[1]); } } while (0)
#define STG_B(t, kh) do { if ((t) < NT) {                         \
    int _b = ((t) & 1) * 32768 + 16384 + (kh) * 8192;             \
    size_t _ko = (size_t)(t) * 64 + (kh) * 32;                    \
    GLDS16(Bt + gB[0] + _ko, lds + _b + ldso[0]);                 \
    GLDS16(Bt + gB[1] + _ko, lds + _b + ldso[1]); } } while (0)

  f32x4 acc[8][4];
#pragma unroll
  for (int i = 0; i < 8; i++)
#pragma unroll
    for (int j = 0; j < 4; j++)
      acc[i][j] = (f32x4){0.f, 0.f, 0.f, 0.f};

  // prologue: tile0 fully + tile1 {A0,B0,A1}; vmcnt(6) -> tile0 landed.
  STG_A(0, 0); STG_B(0, 0); STG_A(0, 1); STG_B(0, 1);
  STG_A(1, 0); STG_B(1, 0); STG_A(1, 1);
  asm volatile("s_waitcnt vmcnt(6)" ::: "memory");
  __builtin_amdgcn_s_barrier();

  const int arow = (wm * 128 + lm) * 32 + sw;   // A frag base (elems, + i*512)
  const int brow = (wn * 64 + lm) * 32 + sw;    // B frag base (elems, + j*512)

  for (int t = 0; t < NT; ++t) {
    const int Ab = (t & 1) * 32768;
    const int Bb = Ab + 16384;
    bf16x8 a[8], b[2];

    // ---- phase 1: k-half 0, col-half 0 ----
#pragma unroll
    for (int i = 0; i < 8; i++) a[i] = *(const bf16x8*)&lds[Ab + arow + i * 512];
    b[0] = *(const bf16x8*)&lds[Bb + brow];
    b[1] = *(const bf16x8*)&lds[Bb + brow + 512];
    STG_B(t + 1, 1);
    __builtin_amdgcn_s_barrier();
    asm volatile("s_waitcnt lgkmcnt(0)" ::: "memory");
    __builtin_amdgcn_s_setprio(1);
#pragma unroll
    for (int i = 0; i < 8; i++) {
      acc[i][0] = __builtin_amdgcn_mfma_f32_16x16x32_bf16(a[i], b[0], acc[i][0], 0, 0, 0);
      acc[i][1] = __builtin_amdgcn_mfma_f32_16x16x32_bf16(a[i], b[1], acc[i][1], 0, 0, 0);
    }
    __builtin_amdgcn_s_setprio(0);
    __builtin_amdgcn_s_barrier();

    // ---- phase 2: k-half 0, col-half 1 ----
    b[0] = *(const bf16x8*)&lds[Bb + brow + 1024];
    b[1] = *(const bf16x8*)&lds[Bb + brow + 1536];
    STG_A(t + 2, 0);
    __builtin_amdgcn_s_barrier();
    asm volatile("s_waitcnt lgkmcnt(0)" ::: "memory");
    __builtin_amdgcn_s_setprio(1);
#pragma unroll
    for (int i = 0; i < 8; i++) {
      acc[i][2] = __builtin_amdgcn_mfma_f32_16x16x32_bf16(a[i], b[0], acc[i][2], 0, 0, 0);
      acc[i][3] = __builtin_amdgcn_mfma_f32_16x16x32_bf16(a[i], b[1], acc[i][3], 0, 0, 0);
    }
    __builtin_amdgcn_s_setprio(0);
    __builtin_amdgcn_s_barrier();

    // ---- phase 3: k-half 1, col-half 0 ----
#pragma unroll
    for (int i = 0; i < 8; i++) a[i] = *(const bf16x8*)&lds[Ab + 8192 + arow + i * 512];
    b[0] = *(const bf16x8*)&lds[Bb + 8192 + brow];
    b[1] = *(const bf16x8*)&lds[Bb + 8192 + brow + 512];
    STG_B(t + 2, 0);
    __builtin_amdgcn_s_barrier();
    asm volatile("s_waitcnt lgkmcnt(0)" ::: "memory");
    __builtin_amdgcn_s_setprio(1);
#pragma unroll
    for (int i = 0; i < 8; i++) {
      acc[i][0] = __builtin_amdgcn_mfma_f32_16x16x32_bf16(a[i], b[0], acc[i][0], 0, 0, 0);
      acc[i][1] = __builtin_amdgcn_mfma_f32_16x16x32_bf16(a[i], b[1], acc[i][1], 0, 0, 0);
    }
    __builtin_amdgcn_s_setprio(0);
    __builtin_amdgcn_s_barrier();

    // ---- phase 4: k-half 1, col-half 1 ----
    b[0] = *(const bf16x8*)&lds[Bb + 8192 + brow + 1024];
    b[1] = *(const bf16x8*)&lds[Bb + 8192 + brow + 1536];
    STG_A(t + 2, 1);
    if (t == NT - 2)     asm volatile("s_waitcnt vmcnt(0)" ::: "memory");
    else if (t < NT - 2) asm volatile("s_waitcnt vmcnt(6)" ::: "memory");
    __builtin_amdgcn_s_barrier();
    asm volatile("s_waitcnt lgkmcnt(0)" ::: "memory");
    __builtin_amdgcn_s_setprio(1);
#pragma unroll
    for (int i = 0; i < 8; i++) {
      acc[i][2] = __builtin_amdgcn_mfma_f32_16x16x32_bf16(a[i], b[0], acc[i][2], 0, 0, 0);
      acc[i][3] = __builtin_amdgcn_mfma_f32_16x16x32_bf16(a[i], b[1], acc[i][3], 0, 0, 0);
    }
    __builtin_amdgcn_s_setprio(0);
    __builtin_amdgcn_s_barrier();
  }

#pragma unroll
  for (int i = 0; i < 8; i++)
#pragma unroll
    for (int j = 0; j < 4; j++)
#pragma unroll
      for (int r = 0; r < 4; r++)
        epi(r0 + wm * 128 + i * 16 + quad * 4 + r, c0 + wn * 64 + j * 16 + lm, acc[i][j][r]);
#undef STG_A
#undef STG_B
}

// ---- common 128x128-tile bf16 MFMA GEMM (kept for score/av): C = A @ Bt^T ----
template <class Epi>
__device__ __forceinline__ void gemm_core(
    const unsigned short* __restrict__ A, int lda,
    const unsigned short* __restrict__ Bt, int ldb,
    int K, int r0, int c0, Epi epi)
{
  extern __shared__ unsigned short sds[];
  unsigned short* As = sds;            // [128][64] bf16, swizzled chunks
  unsigned short* Bs = sds + 128 * 64;
  const int tid  = threadIdx.x;
  const int lane = tid & 63;
  const int wave = tid >> 6;
  const int wr   = (wave >> 1) * 64;
  const int wc   = (wave & 1) * 64;
  const int quad = lane >> 4;
  const int lm   = lane & 15;

  int srow[4], scol[4], sbase[4];
#pragma unroll
  for (int s = 0; s < 4; s++) {
    int chunk = (wave * 4 + s) * 64 + lane;
    srow[s]  = chunk >> 3;
    scol[s]  = ((chunk & 7) ^ (srow[s] & 7)) * 8;
    sbase[s] = (wave * 4 + s) * 512;
  }

  f32x4 acc[4][4];
#pragma unroll
  for (int i = 0; i < 4; i++)
#pragma unroll
    for (int j = 0; j < 4; j++)
      acc[i][j] = (f32x4){0.f, 0.f, 0.f, 0.f};

  for (int k0 = 0; k0 < K; k0 += 64) {
    __syncthreads();
#pragma unroll
    for (int s = 0; s < 4; s++) {
      GLDS16(A  + (size_t)(r0 + srow[s]) * lda + k0 + scol[s], As + sbase[s]);
      GLDS16(Bt + (size_t)(c0 + srow[s]) * ldb + k0 + scol[s], Bs + sbase[s]);
    }
    __syncthreads();
#pragma unroll
    for (int kk = 0; kk < 64; kk += 32) {
      bf16x8 a[4], b[4];
      const int p = (((kk >> 3) + quad) ^ (lm & 7)) * 8;
#pragma unroll
      for (int i = 0; i < 4; i++)
        a[i] = *(const bf16x8*)&As[(wr + i * 16 + lm) * 64 + p];
#pragma unroll
      for (int j = 0; j < 4; j++)
        b[j] = *(const bf16x8*)&Bs[(wc + j * 16 + lm) * 64 + p];
#pragma unroll
      for (int i = 0; i < 4; i++)
#pragma unroll
        for (int j = 0; j < 4; j++)
          acc[i][j] = __builtin_amdgcn_mfma_f32_16x16x32_bf16(a[i], b[j], acc[i][j], 0, 0, 0);
    }
  }
#pragma unroll
  for (int i = 0; i < 4; i++)
#pragma unroll
    for (int j = 0; j < 4; j++)
#pragma unroll
      for (int r = 0; r < 4; r++)
        epi(r0 + wr + i * 16 + quad * 4 + r, c0 + wc + j * 16 + lm, acc[i][j][r]);
}

// ---- conversion kernels ----
__global__ __launch_bounds__(256) void cvt_bf16_kernel(const float* __restrict__ in,
                                                       unsigned short* __restrict__ out) {
  size_t i = ((size_t)blockIdx.x * 256 + threadIdx.x) * 8;
  f32x4 a = *(const f32x4*)&in[i];
  f32x4 b = *(const f32x4*)&in[i + 4];
  u16x8 r;
  r[0] = f2b(a[0]); r[1] = f2b(a[1]); r[2] = f2b(a[2]); r[3] = f2b(a[3]);
  r[4] = f2b(b[0]); r[5] = f2b(b[1]); r[6] = f2b(b[2]); r[7] = f2b(b[3]);
  *(u16x8*)&out[i] = r;
}

// transpose+convert: in fp32 [R,C] (z slices) -> out bf16 [C,R]
__global__ __launch_bounds__(256) void tconv_kernel(const float* __restrict__ in,
                                                    unsigned short* __restrict__ out,
                                                    int R, int C) {
  __shared__ unsigned short tile[32][33];
  int r0 = blockIdx.y * 32, c0 = blockIdx.x * 32;
  const float* inz = in + (size_t)blockIdx.z * R * C;
  unsigned short* outz = out + (size_t)blockIdx.z * R * C;
  int tr = threadIdx.x >> 5;
  int tc = threadIdx.x & 31;
#pragma unroll
  for (int s = 0; s < 4; s++) {
    int r = tr + s * 8;
    tile[r][tc] = f2b(inz[(size_t)(r0 + r) * C + c0 + tc]);
  }
  __syncthreads();
#pragma unroll
  for (int s = 0; s < 4; s++) {
    int r = tr + s * 8;
    outz[(size_t)(c0 + r) * R + r0 + tc] = tile[tc][r];
  }
}

// ---- stage kernels ----
// grid (2, 24, 32): x = 256-col tile within slice, y = z-slice (p*8+h), z = 256-row block
__global__ __launch_bounds__(512) void proj_kernel(const unsigned short* __restrict__ data,
                                                   const unsigned short* __restrict__ Wt,
                                                   unsigned short* __restrict__ q,
                                                   unsigned short* __restrict__ k,
                                                   unsigned short* __restrict__ vt) {
  __shared__ unsigned short lds[65536];   // 128 KB
  int z = blockIdx.y;
  int p = z >> 3, h = z & 7;
  int r0 = blockIdx.z * 256, c0 = blockIdx.x * 256;
  const unsigned short* Bt = Wt + (size_t)z * 512 * 4096;
  if (p == 0) {
    unsigned short* dst = q + (size_t)h * 8192 * 512;
    gemm256(lds, data, 4096, Bt, 4096, 4096, r0, c0,
            [=](int row, int col, float v) { dst[(size_t)row * 512 + col] = f2b(v); });
  } else if (p == 1) {
    unsigned short* dst = k + (size_t)h * 8192 * 512;
    gemm256(lds, data, 4096, Bt, 4096, 4096, r0, c0,
            [=](int row, int col, float v) { dst[(size_t)row * 512 + col] = f2b(v); });
  } else {
    gemm256(lds, data, 4096, Bt, 4096, 4096, r0, c0,
            [=](int row, int col, float v) {
              // b = row>>9, t = row&511 ; v stored transposed per (h,b): [d][t]
              vt[(((size_t)(h * 16 + (row >> 9)) * 512 + col) << 9) + (row & 511)] = f2b(v);
            });
  }
}

// z = h*16+b. S[z][t][s] = (q . k) / 64, fully-masked tiles skipped.
__global__ __launch_bounds__(256) void score_kernel(const unsigned short* __restrict__ q,
                                                    const unsigned short* __restrict__ k,
                                                    unsigned short* __restrict__ S) {
  int z = blockIdx.z;
  int h = z >> 4, b = z & 15;
  int r0 = blockIdx.y * 128, c0 = blockIdx.x * 128;
  if (c0 > r0 + 127) return;  // fully above diagonal
  const unsigned short* A  = q + ((size_t)h * 8192 + b * 512) * 512;
  const unsigned short* Bt = k + ((size_t)h * 8192 + b * 512) * 512;
  unsigned short* Sz = S + (size_t)z * 262144;
  gemm_core(A, 512, Bt, 512, 512, r0, c0,
            [=](int row, int col, float v) { Sz[(size_t)row * 512 + col] = f2b(v * 0.015625f); });
}

// one wave per row of 512; masked (s>t) -> 0 written
__global__ __launch_bounds__(256) void softmax_kernel(unsigned short* __restrict__ S) {
  int row  = blockIdx.x * 4 + (threadIdx.x >> 6);
  int lane = threadIdx.x & 63;
  int t = row & 511;
  unsigned short* pr = S + (size_t)row * 512;
  u16x8 u = *(const u16x8*)&pr[lane * 8];
  float s[8];
  float m = -1e30f;
#pragma unroll
  for (int jj = 0; jj < 8; jj++) {
    int j = lane * 8 + jj;
    s[jj] = (j <= t) ? b2f(u[jj]) : -1e30f;
    m = fmaxf(m, s[jj]);
  }
#pragma unroll
  for (int o = 32; o > 0; o >>= 1) m = fmaxf(m, __shfl_xor(m, o, 64));
  float l = 0.f;
#pragma unroll
  for (int jj = 0; jj < 8; jj++) {
    int j = lane * 8 + jj;
    s[jj] = (j <= t) ? __expf(s[jj] - m) : 0.f;
    l += s[jj];
  }
#pragma unroll
  for (int o = 32; o > 0; o >>= 1) l += __shfl_xor(l, o, 64);
  float inv = 1.f / l;
  u16x8 r;
#pragma unroll
  for (int jj = 0; jj < 8; jj++) r[jj] = f2b(s[jj] * inv);
  *(u16x8*)&pr[lane * 8] = r;
}

// out[b][t][h*512+d] = P @ V ; K trimmed to causal bound (P zeros beyond t anyway)
__global__ __launch_bounds__(256) void av_kernel(const unsigned short* __restrict__ S,
                                                 const unsigned short* __restrict__ vt,
                                                 unsigned short* __restrict__ ao) {
  int z = blockIdx.z;
  int h = z >> 4, b = z & 15;
  int r0 = blockIdx.y * 128, c0 = blockIdx.x * 128;
  const unsigned short* A  = S + (size_t)z * 262144;
  const unsigned short* Bt = vt + (size_t)z * 262144;
  int K = r0 + 128;  // multiple of 64
  gemm_core(A, 512, Bt, 512, K, r0, c0,
            [=](int row, int col, float v) {
              ao[((size_t)(b * 512 + row)) * 4096 + h * 512 + col] = f2b(v);
            });
}

// grid (16, 32): 256x256 tiles of [8192,4096]
__global__ __launch_bounds__(512) void out_kernel(const unsigned short* __restrict__ ao,
                                                  const unsigned short* __restrict__ Wot,
                                                  const float* __restrict__ bo,
                                                  float* __restrict__ out) {
  __shared__ unsigned short lds[65536];   // 128 KB
  int r0 = blockIdx.y * 256, c0 = blockIdx.x * 256;
  gemm256(lds, ao, 4096, Wot, 4096, 4096, r0, c0,
          [=](int row, int col, float v) { out[(size_t)row * 4096 + col] = v + bo[col]; });
}

// ---- launch ----
extern "C" void kernel_launch(void* const* d_in, const int* in_sizes, int n_in,
                              void* d_out, int out_size, void* d_ws, size_t ws_size,
                              hipStream_t stream) {
  const float* data = (const float*)d_in[0];
  const float* Wq = (const float*)d_in[1];
  const float* Wk = (const float*)d_in[2];
  const float* Wv = (const float*)d_in[3];
  const float* Wo = (const float*)d_in[4];
  const float* bo = (const float*)d_in[5];
  float* out = (float*)d_out;

  // workspace layout (bytes); total 402,653,184 (384 MB)
  char* w = (char*)d_ws;
  unsigned short* datab = (unsigned short*)(w);                   // 64 MB  [8192][4096] bf16
  unsigned short* Wt    = (unsigned short*)(w + 67108864ULL);     // 96 MB  [24][512][4096] bf16
  unsigned short* Wot   = (unsigned short*)(w + 167772160ULL);    // 32 MB  [4096][4096] bf16
  unsigned short* qb    = (unsigned short*)(w + 201326592ULL);    // 64 MB  [8][8192][512]
  unsigned short* kb    = (unsigned short*)(w + 268435456ULL);    // 64 MB
  unsigned short* vtb   = (unsigned short*)(w + 335544320ULL);    // 64 MB  [128][512][512]
  unsigned short* Sb    = Wt;     // reuse: weights no longer needed after proj
  unsigned short* aob   = datab;  // reuse: data no longer needed after proj

  const size_t LDS_BYTES = 2 * 128 * 64 * sizeof(unsigned short);  // 32 KB (gemm_core)

  cvt_bf16_kernel<<<16384, 256, 0, stream>>>(data, datab);
  tconv_kernel<<<dim3(16, 128, 8), 256, 0, stream>>>(Wq, Wt, 4096, 512);
  tconv_kernel<<<dim3(16, 128, 8), 256, 0, stream>>>(Wk, Wt + (size_t)8 * 2097152, 4096, 512);
  tconv_kernel<<<dim3(16, 128, 8), 256, 0, stream>>>(Wv, Wt + (size_t)16 * 2097152, 4096, 512);
  tconv_kernel<<<dim3(128, 128, 1), 256, 0, stream>>>(Wo, Wot, 4096, 4096);

  proj_kernel<<<dim3(2, 24, 32), 512, 0, stream>>>(datab, Wt, qb, kb, vtb);
  score_kernel<<<dim3(4, 4, 128), 256, LDS_BYTES, stream>>>(qb, kb, Sb);
  softmax_kernel<<<16384, 256, 0, stream>>>(Sb);
  av_kernel<<<dim3(4, 4, 128), 256, LDS_BYTES, stream>>>(Sb, vtb, aob);
  out_kernel<<<dim3(16, 32, 1), 512, 0, stream>>>(aob, Wot, bo, out);
}